// Round 10
// baseline (1262.664 us; speedup 1.0000x reference)
//
#include <hip/hip_runtime.h>
#include <hip/hip_bf16.h>

#define AF 128
#define BF 128
#define BROWS 32             // rows per fine bucket
#define CAP_F 800            // slots per fine bucket (mean 512, sigma ~23)
#define CROWS 1024           // rows per coarse bucket (= 32 fine)
#define CAP_C 18432          // slots per coarse bucket (mean 16384, sigma 128)
#define CHUNK1 2048
#define NCOARSE_MAX 128

typedef __attribute__((ext_vector_type(8))) short bf16x8;
typedef __attribute__((ext_vector_type(4))) float f32x4;

__device__ inline unsigned short f2bf(float f) {
    unsigned int u = __float_as_uint(f);
    u += 0x7FFF + ((u >> 16) & 1);          // round-to-nearest-even
    return (unsigned short)(u >> 16);
}
__device__ inline unsigned int pk2bf(float x, float y) {
    __hip_bfloat162 h = __float22bfloat162_rn(make_float2(x, y));
    return *(unsigned int*)&h;
}
__device__ inline float bflo(unsigned int u) { return __uint_as_float(u << 16); }
__device__ inline float bfhi(unsigned int u) { return __uint_as_float(u & 0xFFFF0000u); }

// ---- phase1: blocks [0, ngemm) = MFMA GEMM; blocks [ngemm,...) = coarse binning ----
// (R6-proven form: staged W, CHUNK1=2048, segregated dispatch order)
__global__ __launch_bounds__(256) void phase1_kernel(const float* __restrict__ Bin,
                                                     const float* __restrict__ W,
                                                     unsigned int* __restrict__ Sup, int NB,
                                                     const int* __restrict__ rows,
                                                     const int* __restrict__ cols,
                                                     const float* __restrict__ vals,
                                                     int* __restrict__ grelC,
                                                     int2* __restrict__ binnedC,
                                                     int NE, int NCOARSE, int ngemm) {
    __shared__ unsigned short Ws[128][136];
    __shared__ int h[NCOARSE_MAX];
    __shared__ int rbase[NCOARSE_MAX];
    const int tid = threadIdx.x;

    if ((int)blockIdx.x < ngemm) {
        // ---------------- GEMM part ----------------
        const int lane = tid & 63;
        const int wave = tid >> 6;
        const int row0 = blockIdx.x * 64;
        const int m = lane & 15;
        const int quad = lane >> 4;

        {   // stage W transposed: Ws[n][k] = bf16(W[k][n])
            int k = tid >> 1;
            int n0 = (tid & 1) * 64;
            const float4* src = (const float4*)(W + (size_t)k * AF + n0);
            #pragma unroll
            for (int i = 0; i < 16; i++) {
                float4 v = src[i];
                int n = n0 + i * 4;
                Ws[n + 0][k] = f2bf(v.x);
                Ws[n + 1][k] = f2bf(v.y);
                Ws[n + 2][k] = f2bf(v.z);
                Ws[n + 3][k] = f2bf(v.w);
            }
        }
        int arow = row0 + wave * 16 + m;
        int arow_c = (arow < NB) ? arow : (NB - 1);
        const float* ap = Bin + (size_t)arow_c * BF + quad * 8;
        bf16x8 af[4];
        #pragma unroll
        for (int ks = 0; ks < 4; ks++) {
            float4 lo = *(const float4*)(ap + ks * 32);
            float4 hi = *(const float4*)(ap + ks * 32 + 4);
            union { unsigned int u[4]; bf16x8 v; } cv;
            cv.u[0] = pk2bf(lo.x, lo.y); cv.u[1] = pk2bf(lo.z, lo.w);
            cv.u[2] = pk2bf(hi.x, hi.y); cv.u[3] = pk2bf(hi.z, hi.w);
            af[ks] = cv.v;
        }
        __syncthreads();

        f32x4 acc[8];
        #pragma unroll
        for (int nt = 0; nt < 8; nt++) {
            f32x4 a = {0.f, 0.f, 0.f, 0.f};
            #pragma unroll
            for (int ks = 0; ks < 4; ks++) {
                bf16x8 bf = *(const bf16x8*)(&Ws[nt * 16 + m][ks * 32 + quad * 8]);
                a = __builtin_amdgcn_mfma_f32_16x16x32_bf16(af[ks], bf, a, 0, 0, 0);
            }
            acc[nt] = a;
        }
        #pragma unroll
        for (int nt = 0; nt < 4; nt++) {
            #pragma unroll
            for (int r = 0; r < 4; r++) {
                int row = row0 + wave * 16 + quad * 4 + r;
                if (row < NB)
                    Sup[(size_t)row * 64 + nt * 16 + m] = pk2bf(acc[nt][r], acc[nt + 4][r]);
            }
        }
    } else {
        // ---------------- binA part: single global pass, register-staged ----------------
        int bid = blockIdx.x - ngemm;
        int base = bid * CHUNK1;
        int ke[8]; int px[8]; float pv[8];
        #pragma unroll
        for (int i = 0; i < 8; i++) {
            int e = base + tid + i * 256;
            if (e < NE) {
                int r = rows[e];
                ke[i] = r >> 10;
                px[i] = cols[e] | ((r & 1023) << 17);
                pv[i] = vals[e];
            } else ke[i] = -1;
        }
        if (tid < NCOARSE) h[tid] = 0;
        __syncthreads();
        #pragma unroll
        for (int i = 0; i < 8; i++)
            if (ke[i] >= 0) atomicAdd(&h[ke[i]], 1);
        __syncthreads();
        if (tid < NCOARSE) {
            int c = h[tid];
            rbase[tid] = tid * CAP_C + (c ? atomicAdd(&grelC[tid], c) : 0);
            h[tid] = 0;
        }
        __syncthreads();
        #pragma unroll
        for (int i = 0; i < 8; i++) {
            if (ke[i] >= 0) {
                int lp = atomicAdd(&h[ke[i]], 1);
                binnedC[rbase[ke[i]] + lp] = make_int2(px[i], __float_as_int(pv[i]));
            }
        }
    }
}

// ---- passA2: 32 slices per coarse bucket, register-staged single pass ----
__global__ __launch_bounds__(256) void passA2_kernel(const int2* __restrict__ binnedC,
                                                     const int* __restrict__ grelC,
                                                     int* __restrict__ grelF,
                                                     int2* __restrict__ binnedF, int NBUCK) {
    __shared__ int h[32];
    __shared__ int rb[32];
    const int tid = threadIdx.x;
    const int j = blockIdx.x >> 5;      // coarse bucket
    const int s = blockIdx.x & 31;      // slice
    int n = grelC[j]; if (n > CAP_C) n = CAP_C;
    const int st = (n * s) >> 5;
    const int en = (n * (s + 1)) >> 5;  // slice <= 576 <= 3*256
    const int2* src = binnedC + (size_t)j * CAP_C;

    int sub[3]; int qx[3]; int qy[3];
    #pragma unroll
    for (int i = 0; i < 3; i++) {
        int idx = st + tid + i * 256;
        if (idx < en) {
            int2 p = src[idx];
            sub[i] = (p.x >> 22) & 31;      // fine bucket within coarse (localrow >> 5)
            qx[i] = p.x & 0x3FFFFF;         // col(17b) | row-in-fine(5b @ bit17)
            qy[i] = p.y;
        } else sub[i] = -1;
    }
    if (tid < 32) h[tid] = 0;
    __syncthreads();
    #pragma unroll
    for (int i = 0; i < 3; i++)
        if (sub[i] >= 0) atomicAdd(&h[sub[i]], 1);
    __syncthreads();
    if (tid < 32) {
        int c = h[tid];
        int fine = j * 32 + tid;
        rb[tid] = (fine < NBUCK) ? (fine * CAP_F + (c ? atomicAdd(&grelF[fine], c) : 0)) : 0;
        h[tid] = 0;
    }
    __syncthreads();
    #pragma unroll
    for (int i = 0; i < 3; i++) {
        if (sub[i] >= 0) {
            int lp = atomicAdd(&h[sub[i]], 1);
            binnedF[(size_t)rb[sub[i]] + lp] = make_int2(qx[i], qy[i]);
        }
    }
}

// ---- spmm via LDS accumulators: NO sort, NO row-grouping.
// acc[0..2047] = feature plane `lane` (lane-stride-1), acc[2048..4095] = plane `64+lane`.
// Edges processed in arrival order; unsafeAtomicAdd lowers to non-returning
// ds_add_f32 (fire-and-forget) -- plain atomicAdd was a ~215-cycle CAS loop (R9).
__global__ __launch_bounds__(256) void spmm_accum_kernel(const unsigned short* __restrict__ Sup,
                                                         const int2* __restrict__ binned,
                                                         const int* __restrict__ grel,
                                                         const float* __restrict__ bias,
                                                         float* __restrict__ out, int NA) {
    __shared__ __align__(16) int2 spxy[CAP_F];      // 6.4 KB
    __shared__ float acc[BROWS * 128];              // 16 KB: [row*64+lane] = feat lane, +2048 = feat 64+lane
    const int tid = threadIdx.x;
    const int b = blockIdx.x;
    int n = grel[b]; if (n > CAP_F) n = CAP_F;
    const int2* src = binned + (size_t)b * CAP_F;

    #pragma unroll
    for (int j = 0; j < 4; j++) {
        int i = tid + j * 256;
        if (i < n) spxy[i] = src[i];
    }
    float4* az = (float4*)acc;
    #pragma unroll
    for (int j = 0; j < 4; j++) az[tid + j * 256] = make_float4(0.f, 0.f, 0.f, 0.f);
    __syncthreads();

    const int lane = tid & 63;
    const int wv = tid >> 6;
    // wave wv owns edge range [st, en); st 8-aligned so int4 LDS reads stay aligned
    int st = ((n * wv) >> 2) & ~7;
    int en = (wv == 3) ? n : (((n * (wv + 1)) >> 2) & ~7);

    int i = st;
    for (; i + 8 <= en; i += 8) {
        int4 qa = *(const int4*)&spxy[i];
        int4 qb = *(const int4*)&spxy[i + 2];
        int4 qc = *(const int4*)&spxy[i + 4];
        int4 qd = *(const int4*)&spxy[i + 6];
        int cx[8], cy[8];
        cx[0] = qa.x; cy[0] = qa.y; cx[1] = qa.z; cy[1] = qa.w;
        cx[2] = qb.x; cy[2] = qb.y; cx[3] = qb.z; cy[3] = qb.w;
        cx[4] = qc.x; cy[4] = qc.y; cx[5] = qc.z; cy[5] = qc.w;
        cx[6] = qd.x; cy[6] = qd.y; cx[7] = qd.z; cy[7] = qd.w;
        unsigned int su[8];
        #pragma unroll
        for (int t = 0; t < 8; t++)
            su[t] = *(const unsigned int*)(Sup + (size_t)(cx[t] & 0x1FFFF) * AF + lane * 2);
        #pragma unroll
        for (int t = 0; t < 8; t++) {
            int idx = ((cx[t] >> 17) & 31) * 64 + lane;
            float v = __int_as_float(cy[t]);
            unsafeAtomicAdd(&acc[idx], v * bflo(su[t]));
            unsafeAtomicAdd(&acc[idx + 2048], v * bfhi(su[t]));
        }
    }
    for (; i < en; ++i) {                    // wave-uniform tail (wave 3 only, <8 edges)
        int2 q = spxy[i];
        unsigned int su = *(const unsigned int*)(Sup + (size_t)(q.x & 0x1FFFF) * AF + lane * 2);
        int idx = ((q.x >> 17) & 31) * 64 + lane;
        float v = __int_as_float(q.y);
        unsafeAtomicAdd(&acc[idx], v * bflo(su));
        unsafeAtomicAdd(&acc[idx + 2048], v * bfhi(su));
    }
    __syncthreads();

    // epilogue: acc[r*64+lane] is feature `lane`, acc[..+2048] is feature `64+lane`
    // (same layout as the proven sorted kernel's ax/ay) -> scalar coalesced stores.
    const float b0 = bias[lane];
    const float b1 = bias[64 + lane];
    #pragma unroll
    for (int k = 0; k < 8; k++) {
        int r = wv * 8 + k;
        int row = b * BROWS + r;
        if (row < NA) {
            out[(size_t)row * AF + lane]      = acc[r * 64 + lane] + b0;
            out[(size_t)row * AF + 64 + lane] = acc[r * 64 + lane + 2048] + b1;
        }
    }
}

extern "C" void kernel_launch(void* const* d_in, const int* in_sizes, int n_in,
                              void* d_out, int out_size, void* d_ws, size_t ws_size,
                              hipStream_t stream) {
    const float* b_input   = (const float*)d_in[0];
    const int*   edge_rows = (const int*)d_in[1];
    const int*   edge_cols = (const int*)d_in[2];
    const float* edge_vals = (const float*)d_in[3];
    const float* a_weight  = (const float*)d_in[4];
    const float* a_bias    = (const float*)d_in[5];
    const int NB = in_sizes[0] / BF;
    const int NE = in_sizes[1];
    const int NA = out_size / AF;
    const int NBUCK = (NA + BROWS - 1) / BROWS;     // 3125 fine buckets
    const int NCOARSE = (NA + CROWS - 1) / CROWS;   // 98 coarse buckets
    float* out = (float*)d_out;

    char* ws = (char*)d_ws;
    size_t off = 0;
    unsigned short* Sup = (unsigned short*)(ws + off); off += (size_t)NB * AF * sizeof(unsigned short);
    int* grelC = (int*)(ws + off); off += 1024 * sizeof(int);
    int* grelF = (int*)(ws + off); off += 3328 * sizeof(int);
    int2* binnedC = (int2*)(ws + off); off += (size_t)NCOARSE * CAP_C * sizeof(int2);
    int2* binnedF = (int2*)(ws + off); off += (size_t)NBUCK * CAP_F * sizeof(int2);
    (void)ws_size; (void)n_in;

    hipMemsetAsync(grelC, 0, (1024 + 3328) * sizeof(int), stream);   // grelC + grelF contiguous

    const int ngemm = (NB + 63) / 64;                 // 1563
    const int npass = (NE + CHUNK1 - 1) / CHUNK1;     // 782
    phase1_kernel<<<ngemm + npass, 256, 0, stream>>>(
        b_input, a_weight, (unsigned int*)Sup, NB,
        edge_rows, edge_cols, edge_vals, grelC, binnedC, NE, NCOARSE, ngemm);
    passA2_kernel<<<NCOARSE * 32, 256, 0, stream>>>(binnedC, grelC, grelF, binnedF, NBUCK);
    spmm_accum_kernel<<<NBUCK, 256, 0, stream>>>(Sup, binnedF, grelF, a_bias, out, NA);
}

// Round 11
// 213.996 us; speedup vs baseline: 5.9004x; 5.9004x over previous
//
#include <hip/hip_runtime.h>
#include <hip/hip_bf16.h>

#define AF 128
#define BF 128
#define BROWS 32             // rows per fine bucket
#define CAP_F 800            // slots per fine bucket (mean 512, sigma ~23)
#define SORT_CAP 1024        // CAP_F + 32*7 = provable worst-case x8 row padding
#define CROWS 1024           // rows per coarse bucket (= 32 fine)
#define CAP_C 18432          // slots per coarse bucket (mean 16384, sigma 128)
#define CHUNK1 2048
#define GTILES 4             // row-tiles (of 64) per GEMM block
#define NCOARSE_MAX 128

typedef __attribute__((ext_vector_type(8))) short bf16x8;
typedef __attribute__((ext_vector_type(4))) float f32x4;

__device__ inline unsigned short f2bf(float f) {
    unsigned int u = __float_as_uint(f);
    u += 0x7FFF + ((u >> 16) & 1);          // round-to-nearest-even
    return (unsigned short)(u >> 16);
}
__device__ inline unsigned int pk2bf(float x, float y) {
    __hip_bfloat162 h = __float22bfloat162_rn(make_float2(x, y));
    return *(unsigned int*)&h;
}
__device__ inline float bflo(unsigned int u) { return __uint_as_float(u << 16); }
__device__ inline float bfhi(unsigned int u) { return __uint_as_float(u & 0xFFFF0000u); }

// ---- phase1: blocks [0, ngemm) = MFMA GEMM (4 row-tiles each); rest = coarse binning ----
__global__ __launch_bounds__(256) void phase1_kernel(const float* __restrict__ Bin,
                                                     const float* __restrict__ W,
                                                     unsigned int* __restrict__ Sup, int NB,
                                                     const int* __restrict__ rows,
                                                     const int* __restrict__ cols,
                                                     const float* __restrict__ vals,
                                                     int* __restrict__ grelC,
                                                     int2* __restrict__ binnedC,
                                                     int NE, int NCOARSE, int ngemm) {
    __shared__ unsigned short Ws[128][136];
    __shared__ int h[NCOARSE_MAX];
    __shared__ int rbase[NCOARSE_MAX];
    const int tid = threadIdx.x;

    if ((int)blockIdx.x < ngemm) {
        // ---------------- GEMM part: stage W once, compute GTILES row-tiles ----------------
        const int lane = tid & 63;
        const int wave = tid >> 6;
        const int m = lane & 15;
        const int quad = lane >> 4;

        {   // stage W transposed: Ws[n][k] = bf16(W[k][n])
            int k = tid >> 1;
            int n0 = (tid & 1) * 64;
            const float4* src = (const float4*)(W + (size_t)k * AF + n0);
            #pragma unroll
            for (int i = 0; i < 16; i++) {
                float4 v = src[i];
                int n = n0 + i * 4;
                Ws[n + 0][k] = f2bf(v.x);
                Ws[n + 1][k] = f2bf(v.y);
                Ws[n + 2][k] = f2bf(v.z);
                Ws[n + 3][k] = f2bf(v.w);
            }
        }
        __syncthreads();

        const int row00 = blockIdx.x * (64 * GTILES);
        for (int t = 0; t < GTILES; t++) {
            const int row0 = row00 + t * 64;
            if (row0 >= NB) break;
            int arow = row0 + wave * 16 + m;
            int arow_c = (arow < NB) ? arow : (NB - 1);
            const float* ap = Bin + (size_t)arow_c * BF + quad * 8;
            bf16x8 af[4];
            #pragma unroll
            for (int ks = 0; ks < 4; ks++) {
                float4 lo = *(const float4*)(ap + ks * 32);
                float4 hi = *(const float4*)(ap + ks * 32 + 4);
                union { unsigned int u[4]; bf16x8 v; } cv;
                cv.u[0] = pk2bf(lo.x, lo.y); cv.u[1] = pk2bf(lo.z, lo.w);
                cv.u[2] = pk2bf(hi.x, hi.y); cv.u[3] = pk2bf(hi.z, hi.w);
                af[ks] = cv.v;
            }

            f32x4 acc[8];
            #pragma unroll
            for (int nt = 0; nt < 8; nt++) {
                f32x4 a = {0.f, 0.f, 0.f, 0.f};
                #pragma unroll
                for (int ks = 0; ks < 4; ks++) {
                    bf16x8 bf = *(const bf16x8*)(&Ws[nt * 16 + m][ks * 32 + quad * 8]);
                    a = __builtin_amdgcn_mfma_f32_16x16x32_bf16(af[ks], bf, a, 0, 0, 0);
                }
                acc[nt] = a;
            }
            #pragma unroll
            for (int nt = 0; nt < 4; nt++) {
                #pragma unroll
                for (int r = 0; r < 4; r++) {
                    int row = row0 + wave * 16 + quad * 4 + r;
                    if (row < NB)
                        Sup[(size_t)row * 64 + nt * 16 + m] = pk2bf(acc[nt][r], acc[nt + 4][r]);
                }
            }
        }
    } else {
        // ---------------- binA part: single global pass, register-staged (R6-proven) ----------------
        int bid = blockIdx.x - ngemm;
        int base = bid * CHUNK1;
        int ke[8]; int px[8]; float pv[8];
        #pragma unroll
        for (int i = 0; i < 8; i++) {
            int e = base + tid + i * 256;
            if (e < NE) {
                int r = rows[e];
                ke[i] = r >> 10;
                px[i] = cols[e] | ((r & 1023) << 17);
                pv[i] = vals[e];
            } else ke[i] = -1;
        }
        if (tid < NCOARSE) h[tid] = 0;
        __syncthreads();
        #pragma unroll
        for (int i = 0; i < 8; i++)
            if (ke[i] >= 0) atomicAdd(&h[ke[i]], 1);
        __syncthreads();
        if (tid < NCOARSE) {
            int c = h[tid];
            rbase[tid] = tid * CAP_C + (c ? atomicAdd(&grelC[tid], c) : 0);
            h[tid] = 0;
        }
        __syncthreads();
        #pragma unroll
        for (int i = 0; i < 8; i++) {
            if (ke[i] >= 0) {
                int lp = atomicAdd(&h[ke[i]], 1);
                binnedC[rbase[ke[i]] + lp] = make_int2(px[i], __float_as_int(pv[i]));
            }
        }
    }
}

// ---- passA2: 32 slices per coarse bucket, register-staged single pass ----
__global__ __launch_bounds__(256) void passA2_kernel(const int2* __restrict__ binnedC,
                                                     const int* __restrict__ grelC,
                                                     int* __restrict__ grelF,
                                                     int2* __restrict__ binnedF, int NBUCK) {
    __shared__ int h[32];
    __shared__ int rb[32];
    const int tid = threadIdx.x;
    const int j = blockIdx.x >> 5;      // coarse bucket
    const int s = blockIdx.x & 31;      // slice
    int n = grelC[j]; if (n > CAP_C) n = CAP_C;
    const int st = (n * s) >> 5;
    const int en = (n * (s + 1)) >> 5;  // slice <= 576 <= 3*256
    const int2* src = binnedC + (size_t)j * CAP_C;

    int sub[3]; int qx[3]; int qy[3];
    #pragma unroll
    for (int i = 0; i < 3; i++) {
        int idx = st + tid + i * 256;
        if (idx < en) {
            int2 p = src[idx];
            sub[i] = (p.x >> 22) & 31;      // fine bucket within coarse (localrow >> 5)
            qx[i] = p.x & 0x3FFFFF;         // col(17b) | row-in-fine(5b @ bit17)
            qy[i] = p.y;
        } else sub[i] = -1;
    }
    if (tid < 32) h[tid] = 0;
    __syncthreads();
    #pragma unroll
    for (int i = 0; i < 3; i++)
        if (sub[i] >= 0) atomicAdd(&h[sub[i]], 1);
    __syncthreads();
    if (tid < 32) {
        int c = h[tid];
        int fine = j * 32 + tid;
        rb[tid] = (fine < NBUCK) ? (fine * CAP_F + (c ? atomicAdd(&grelF[fine], c) : 0)) : 0;
        h[tid] = 0;
    }
    __syncthreads();
    #pragma unroll
    for (int i = 0; i < 3; i++) {
        if (sub[i] >= 0) {
            int lp = atomicAdd(&h[sub[i]], 1);
            binnedF[(size_t)rb[sub[i]] + lp] = make_int2(qx[i], qy[i]);
        }
    }
}

// ---- fused per-bucket sort + pipelined banded gather; rows padded to x8 (R6-proven) ----
__global__ __launch_bounds__(256) void spmm_sorted_kernel(const unsigned short* __restrict__ Sup,
                                                          const int2* __restrict__ binned,
                                                          const int* __restrict__ grel,
                                                          const float* __restrict__ bias,
                                                          float* __restrict__ out, int NA) {
    __shared__ int2 spxy[SORT_CAP];
    __shared__ int cnt[BROWS];
    __shared__ int rs[BROWS + 1];
    __shared__ int cur[BROWS];
    const int tid = threadIdx.x;
    const int b = blockIdx.x;
    int n = grel[b]; if (n > CAP_F) n = CAP_F;
    const int2* src = binned + (size_t)b * CAP_F;

    int2 pr[4];
    #pragma unroll
    for (int j = 0; j < 4; j++) {
        int i = tid + j * 256;
        pr[j] = (i < n) ? src[i] : make_int2(-1, 0);
    }
    if (tid < BROWS) cnt[tid] = 0;
    __syncthreads();
    #pragma unroll
    for (int j = 0; j < 4; j++)
        if (pr[j].x >= 0) atomicAdd(&cnt[(pr[j].x >> 17) & 31], 1);
    __syncthreads();
    // lanes 0..31 of wave 0: shfl scan over 32 counters (padded to x8)
    if (tid < 32) {
        int v = (cnt[tid] + 7) & ~7;
        int x = v;
        #pragma unroll
        for (int off = 1; off < 32; off <<= 1) {
            int t = __shfl_up(x, off);
            if (tid >= off) x += t;
        }
        rs[tid] = x - v;
        cur[tid] = x - v;
        if (tid == 31) rs[32] = x;
    }
    __syncthreads();
    #pragma unroll
    for (int j = 0; j < 4; j++) {
        if (pr[j].x >= 0) {
            int lr = (pr[j].x >> 17) & 31;
            int pos = atomicAdd(&cur[lr], 1);
            spxy[pos] = make_int2(pr[j].x & 0x1FFFF, pr[j].y);
        }
    }
    __syncthreads();
    if (tid < BROWS) {      // pad slots: col 0, val 0 contribute nothing (Sup row 0 stays L1-hot)
        int end = rs[tid + 1];
        for (int p = cur[tid]; p < end; p++) spxy[p] = make_int2(0, 0);
    }
    __syncthreads();

    // ---- pipelined gather: wave wv owns contiguous rows [wv*8, wv*8+8).
    const int lane = tid & 63;
    const int wv = tid >> 6;
    const float b0 = bias[lane];
    const float b1 = bias[64 + lane];
    int r = wv * 8;
    const int rend = r + 8;
    int e = rs[r];
    const int eend = rs[rend];
    int nb = rs[r + 1];
    float ax = 0.f, ay = 0.f;

    int2 q[8]; unsigned int su[8];
    if (e < eend) {
        #pragma unroll
        for (int t = 0; t < 8; t++) q[t] = spxy[e + t];
        #pragma unroll
        for (int t = 0; t < 8; t++)
            su[t] = *(const unsigned int*)(Sup + (size_t)q[t].x * AF + lane * 2);
    }
    while (e < eend) {
        const int en2 = e + 8;
        int2 q2[8]; unsigned int s2[8];
        if (en2 < eend) {                       // wave-uniform branch
            #pragma unroll
            for (int t = 0; t < 8; t++) q2[t] = spxy[en2 + t];
            #pragma unroll
            for (int t = 0; t < 8; t++)
                s2[t] = *(const unsigned int*)(Sup + (size_t)q2[t].x * AF + lane * 2);
        }
        while (e >= nb) {                       // flush finished rows (empties get bias-only)
            int row = b * BROWS + r;
            if (row < NA) {
                out[(size_t)row * AF + lane]      = ax + b0;
                out[(size_t)row * AF + 64 + lane] = ay + b1;
            }
            ax = 0.f; ay = 0.f;
            ++r; nb = rs[r + 1];
        }
        #pragma unroll
        for (int t = 0; t < 8; t++) {
            float v = __int_as_float(q[t].y);
            ax += v * bflo(su[t]);
            ay += v * bfhi(su[t]);
        }
        #pragma unroll
        for (int t = 0; t < 8; t++) { q[t] = q2[t]; su[t] = s2[t]; }
        e = en2;
    }
    while (r < rend) {                          // trailing rows (incl. last accumulated one)
        int row = b * BROWS + r;
        if (row < NA) {
            out[(size_t)row * AF + lane]      = ax + b0;
            out[(size_t)row * AF + 64 + lane] = ay + b1;
        }
        ax = 0.f; ay = 0.f;
        ++r;
    }
}

extern "C" void kernel_launch(void* const* d_in, const int* in_sizes, int n_in,
                              void* d_out, int out_size, void* d_ws, size_t ws_size,
                              hipStream_t stream) {
    const float* b_input   = (const float*)d_in[0];
    const int*   edge_rows = (const int*)d_in[1];
    const int*   edge_cols = (const int*)d_in[2];
    const float* edge_vals = (const float*)d_in[3];
    const float* a_weight  = (const float*)d_in[4];
    const float* a_bias    = (const float*)d_in[5];
    const int NB = in_sizes[0] / BF;
    const int NE = in_sizes[1];
    const int NA = out_size / AF;
    const int NBUCK = (NA + BROWS - 1) / BROWS;     // 3125 fine buckets
    const int NCOARSE = (NA + CROWS - 1) / CROWS;   // 98 coarse buckets
    float* out = (float*)d_out;

    char* ws = (char*)d_ws;
    size_t off = 0;
    unsigned short* Sup = (unsigned short*)(ws + off); off += (size_t)NB * AF * sizeof(unsigned short);
    int* grelC = (int*)(ws + off); off += 1024 * sizeof(int);
    int* grelF = (int*)(ws + off); off += 3328 * sizeof(int);
    int2* binnedC = (int2*)(ws + off); off += (size_t)NCOARSE * CAP_C * sizeof(int2);
    int2* binnedF = (int2*)(ws + off); off += (size_t)NBUCK * CAP_F * sizeof(int2);
    (void)ws_size; (void)n_in;

    hipMemsetAsync(grelC, 0, (1024 + 3328) * sizeof(int), stream);   // grelC + grelF contiguous

    const int ngemm = (NB + 64 * GTILES - 1) / (64 * GTILES);   // 391
    const int npass = (NE + CHUNK1 - 1) / CHUNK1;               // 782
    phase1_kernel<<<ngemm + npass, 256, 0, stream>>>(
        b_input, a_weight, (unsigned int*)Sup, NB,
        edge_rows, edge_cols, edge_vals, grelC, binnedC, NE, NCOARSE, ngemm);
    passA2_kernel<<<NCOARSE * 32, 256, 0, stream>>>(binnedC, grelC, grelF, binnedF, NBUCK);
    spmm_sorted_kernel<<<NBUCK, 256, 0, stream>>>(Sup, binnedF, grelF, a_bias, out, NA);
}

// Round 12
// 211.190 us; speedup vs baseline: 5.9788x; 1.0133x over previous
//
#include <hip/hip_runtime.h>
#include <hip/hip_bf16.h>

#define AF 128
#define BF 128
#define BROWS 16             // rows per fine bucket
#define CAP_F 400            // slots per fine bucket (mean 256, sigma 16 -> 9 sigma margin)
#define SORT_CAP 512         // CAP_F + 16*7 = exact worst-case x8 row padding
#define CROWS 1024           // rows per coarse bucket (= 64 fine)
#define CAP_C 18432          // slots per coarse bucket (mean 16384, sigma 128)
#define CHUNK1 2048
#define GTILES 4             // row-tiles (of 64) per GEMM block
#define NCOARSE_MAX 128

typedef __attribute__((ext_vector_type(8))) short bf16x8;
typedef __attribute__((ext_vector_type(4))) float f32x4;

__device__ inline unsigned short f2bf(float f) {
    unsigned int u = __float_as_uint(f);
    u += 0x7FFF + ((u >> 16) & 1);          // round-to-nearest-even
    return (unsigned short)(u >> 16);
}
__device__ inline unsigned int pk2bf(float x, float y) {
    __hip_bfloat162 h = __float22bfloat162_rn(make_float2(x, y));
    return *(unsigned int*)&h;
}
__device__ inline float bflo(unsigned int u) { return __uint_as_float(u << 16); }
__device__ inline float bfhi(unsigned int u) { return __uint_as_float(u & 0xFFFF0000u); }

// ---- phase1: blocks [0, ngemm) = MFMA GEMM (4 row-tiles each); rest = coarse binning ----
__global__ __launch_bounds__(256) void phase1_kernel(const float* __restrict__ Bin,
                                                     const float* __restrict__ W,
                                                     unsigned int* __restrict__ Sup, int NB,
                                                     const int* __restrict__ rows,
                                                     const int* __restrict__ cols,
                                                     const float* __restrict__ vals,
                                                     int* __restrict__ grelC,
                                                     int2* __restrict__ binnedC,
                                                     int NE, int NCOARSE, int ngemm) {
    __shared__ unsigned short Ws[128][136];
    __shared__ int h[NCOARSE_MAX];
    __shared__ int rbase[NCOARSE_MAX];
    const int tid = threadIdx.x;

    if ((int)blockIdx.x < ngemm) {
        // ---------------- GEMM part: stage W once, compute GTILES row-tiles ----------------
        const int lane = tid & 63;
        const int wave = tid >> 6;
        const int m = lane & 15;
        const int quad = lane >> 4;

        {   // stage W transposed: Ws[n][k] = bf16(W[k][n])
            int k = tid >> 1;
            int n0 = (tid & 1) * 64;
            const float4* src = (const float4*)(W + (size_t)k * AF + n0);
            #pragma unroll
            for (int i = 0; i < 16; i++) {
                float4 v = src[i];
                int n = n0 + i * 4;
                Ws[n + 0][k] = f2bf(v.x);
                Ws[n + 1][k] = f2bf(v.y);
                Ws[n + 2][k] = f2bf(v.z);
                Ws[n + 3][k] = f2bf(v.w);
            }
        }
        __syncthreads();

        const int row00 = blockIdx.x * (64 * GTILES);
        for (int t = 0; t < GTILES; t++) {
            const int row0 = row00 + t * 64;
            if (row0 >= NB) break;
            int arow = row0 + wave * 16 + m;
            int arow_c = (arow < NB) ? arow : (NB - 1);
            const float* ap = Bin + (size_t)arow_c * BF + quad * 8;
            bf16x8 af[4];
            #pragma unroll
            for (int ks = 0; ks < 4; ks++) {
                float4 lo = *(const float4*)(ap + ks * 32);
                float4 hi = *(const float4*)(ap + ks * 32 + 4);
                union { unsigned int u[4]; bf16x8 v; } cv;
                cv.u[0] = pk2bf(lo.x, lo.y); cv.u[1] = pk2bf(lo.z, lo.w);
                cv.u[2] = pk2bf(hi.x, hi.y); cv.u[3] = pk2bf(hi.z, hi.w);
                af[ks] = cv.v;
            }

            f32x4 acc[8];
            #pragma unroll
            for (int nt = 0; nt < 8; nt++) {
                f32x4 a = {0.f, 0.f, 0.f, 0.f};
                #pragma unroll
                for (int ks = 0; ks < 4; ks++) {
                    bf16x8 bf = *(const bf16x8*)(&Ws[nt * 16 + m][ks * 32 + quad * 8]);
                    a = __builtin_amdgcn_mfma_f32_16x16x32_bf16(af[ks], bf, a, 0, 0, 0);
                }
                acc[nt] = a;
            }
            #pragma unroll
            for (int nt = 0; nt < 4; nt++) {
                #pragma unroll
                for (int r = 0; r < 4; r++) {
                    int row = row0 + wave * 16 + quad * 4 + r;
                    if (row < NB)
                        Sup[(size_t)row * 64 + nt * 16 + m] = pk2bf(acc[nt][r], acc[nt + 4][r]);
                }
            }
        }
    } else {
        // ---------------- binA part: single global pass, register-staged (R6-proven) ----------------
        int bid = blockIdx.x - ngemm;
        int base = bid * CHUNK1;
        int ke[8]; int px[8]; float pv[8];
        #pragma unroll
        for (int i = 0; i < 8; i++) {
            int e = base + tid + i * 256;
            if (e < NE) {
                int r = rows[e];
                ke[i] = r >> 10;
                px[i] = cols[e] | ((r & 1023) << 17);
                pv[i] = vals[e];
            } else ke[i] = -1;
        }
        if (tid < NCOARSE) h[tid] = 0;
        __syncthreads();
        #pragma unroll
        for (int i = 0; i < 8; i++)
            if (ke[i] >= 0) atomicAdd(&h[ke[i]], 1);
        __syncthreads();
        if (tid < NCOARSE) {
            int c = h[tid];
            rbase[tid] = tid * CAP_C + (c ? atomicAdd(&grelC[tid], c) : 0);
            h[tid] = 0;
        }
        __syncthreads();
        #pragma unroll
        for (int i = 0; i < 8; i++) {
            if (ke[i] >= 0) {
                int lp = atomicAdd(&h[ke[i]], 1);
                binnedC[rbase[ke[i]] + lp] = make_int2(px[i], __float_as_int(pv[i]));
            }
        }
    }
}

// ---- passA2: 16 slices per coarse bucket -> 64 fine bins each; 1152-edge slices keep
// 18-edge (144B) scatter runs per fine bin (write-coalescing preserved, R5 lesson) ----
__global__ __launch_bounds__(256) void passA2_kernel(const int2* __restrict__ binnedC,
                                                     const int* __restrict__ grelC,
                                                     int* __restrict__ grelF,
                                                     int2* __restrict__ binnedF, int NBUCK) {
    __shared__ int h[64];
    __shared__ int rb[64];
    const int tid = threadIdx.x;
    const int j = blockIdx.x >> 4;      // coarse bucket
    const int s = blockIdx.x & 15;      // slice
    int n = grelC[j]; if (n > CAP_C) n = CAP_C;
    const int st = (n * s) >> 4;
    const int en = (n * (s + 1)) >> 4;  // slice <= 1153 <= 5*256
    const int2* src = binnedC + (size_t)j * CAP_C;

    int sub[5]; int qx[5]; int qy[5];
    #pragma unroll
    for (int i = 0; i < 5; i++) {
        int idx = st + tid + i * 256;
        if (idx < en) {
            int2 p = src[idx];
            sub[i] = (p.x >> 21) & 63;      // fine bucket within coarse (localrow >> 4)
            qx[i] = p.x & 0x1FFFFF;         // col(17b) | row-in-fine(4b @ bit17)
            qy[i] = p.y;
        } else sub[i] = -1;
    }
    if (tid < 64) h[tid] = 0;
    __syncthreads();
    #pragma unroll
    for (int i = 0; i < 5; i++)
        if (sub[i] >= 0) atomicAdd(&h[sub[i]], 1);
    __syncthreads();
    if (tid < 64) {
        int c = h[tid];
        int fine = j * 64 + tid;
        rb[tid] = (fine < NBUCK) ? (fine * CAP_F + (c ? atomicAdd(&grelF[fine], c) : 0)) : 0;
        h[tid] = 0;
    }
    __syncthreads();
    #pragma unroll
    for (int i = 0; i < 5; i++) {
        if (sub[i] >= 0) {
            int lp = atomicAdd(&h[sub[i]], 1);
            binnedF[(size_t)rb[sub[i]] + lp] = make_int2(qx[i], qy[i]);
        }
    }
}

// ---- fused per-bucket sort + pipelined banded gather; rows padded to x8 ----
__global__ __launch_bounds__(256) void spmm_sorted_kernel(const unsigned short* __restrict__ Sup,
                                                          const int2* __restrict__ binned,
                                                          const int* __restrict__ grel,
                                                          const float* __restrict__ bias,
                                                          float* __restrict__ out, int NA) {
    __shared__ int2 spxy[SORT_CAP];
    __shared__ int cnt[BROWS];
    __shared__ int rs[BROWS + 1];
    __shared__ int cur[BROWS];
    const int tid = threadIdx.x;
    const int b = blockIdx.x;
    int n = grel[b]; if (n > CAP_F) n = CAP_F;
    const int2* src = binned + (size_t)b * CAP_F;

    int2 pr[2];
    #pragma unroll
    for (int j = 0; j < 2; j++) {
        int i = tid + j * 256;
        pr[j] = (i < n) ? src[i] : make_int2(-1, 0);
    }
    if (tid < BROWS) cnt[tid] = 0;
    __syncthreads();
    #pragma unroll
    for (int j = 0; j < 2; j++)
        if (pr[j].x >= 0) atomicAdd(&cnt[(pr[j].x >> 17) & 15], 1);
    __syncthreads();
    // lanes 0..15 of wave 0: shfl scan over 16 counters (padded to x8)
    if (tid < 16) {
        int v = (cnt[tid] + 7) & ~7;
        int x = v;
        #pragma unroll
        for (int off = 1; off < 16; off <<= 1) {
            int t = __shfl_up(x, off);
            if (tid >= off) x += t;
        }
        rs[tid] = x - v;
        cur[tid] = x - v;
        if (tid == 15) rs[16] = x;
    }
    __syncthreads();
    #pragma unroll
    for (int j = 0; j < 2; j++) {
        if (pr[j].x >= 0) {
            int lr = (pr[j].x >> 17) & 15;
            int pos = atomicAdd(&cur[lr], 1);
            spxy[pos] = make_int2(pr[j].x & 0x1FFFF, pr[j].y);
        }
    }
    __syncthreads();
    if (tid < BROWS) {      // pad slots: col 0, val 0 contribute nothing (Sup row 0 stays L1-hot)
        int end = rs[tid + 1];
        for (int p = cur[tid]; p < end; p++) spxy[p] = make_int2(0, 0);
    }
    __syncthreads();

    // ---- pipelined gather: wave wv owns contiguous rows [wv*4, wv*4+4).
    const int lane = tid & 63;
    const int wv = tid >> 6;
    const float b0 = bias[lane];
    const float b1 = bias[64 + lane];
    int r = wv * 4;
    const int rend = r + 4;
    int e = rs[r];
    const int eend = rs[rend];
    int nb = rs[r + 1];
    float ax = 0.f, ay = 0.f;

    int2 q[8]; unsigned int su[8];
    if (e < eend) {
        #pragma unroll
        for (int t = 0; t < 8; t++) q[t] = spxy[e + t];
        #pragma unroll
        for (int t = 0; t < 8; t++)
            su[t] = *(const unsigned int*)(Sup + (size_t)q[t].x * AF + lane * 2);
    }
    while (e < eend) {
        const int en2 = e + 8;
        int2 q2[8]; unsigned int s2[8];
        if (en2 < eend) {                       // wave-uniform branch
            #pragma unroll
            for (int t = 0; t < 8; t++) q2[t] = spxy[en2 + t];
            #pragma unroll
            for (int t = 0; t < 8; t++)
                s2[t] = *(const unsigned int*)(Sup + (size_t)q2[t].x * AF + lane * 2);
        }
        while (e >= nb) {                       // flush finished rows (empties get bias-only)
            int row = b * BROWS + r;
            if (row < NA) {
                out[(size_t)row * AF + lane]      = ax + b0;
                out[(size_t)row * AF + 64 + lane] = ay + b1;
            }
            ax = 0.f; ay = 0.f;
            ++r; nb = rs[r + 1];
        }
        #pragma unroll
        for (int t = 0; t < 8; t++) {
            float v = __int_as_float(q[t].y);
            ax += v * bflo(su[t]);
            ay += v * bfhi(su[t]);
        }
        #pragma unroll
        for (int t = 0; t < 8; t++) { q[t] = q2[t]; su[t] = s2[t]; }
        e = en2;
    }
    while (r < rend) {                          // trailing rows (incl. last accumulated one)
        int row = b * BROWS + r;
        if (row < NA) {
            out[(size_t)row * AF + lane]      = ax + b0;
            out[(size_t)row * AF + 64 + lane] = ay + b1;
        }
        ax = 0.f; ay = 0.f;
        ++r;
    }
}

extern "C" void kernel_launch(void* const* d_in, const int* in_sizes, int n_in,
                              void* d_out, int out_size, void* d_ws, size_t ws_size,
                              hipStream_t stream) {
    const float* b_input   = (const float*)d_in[0];
    const int*   edge_rows = (const int*)d_in[1];
    const int*   edge_cols = (const int*)d_in[2];
    const float* edge_vals = (const float*)d_in[3];
    const float* a_weight  = (const float*)d_in[4];
    const float* a_bias    = (const float*)d_in[5];
    const int NB = in_sizes[0] / BF;
    const int NE = in_sizes[1];
    const int NA = out_size / AF;
    const int NBUCK = (NA + BROWS - 1) / BROWS;     // 6250 fine buckets
    const int NCOARSE = (NA + CROWS - 1) / CROWS;   // 98 coarse buckets
    float* out = (float*)d_out;

    char* ws = (char*)d_ws;
    size_t off = 0;
    unsigned short* Sup = (unsigned short*)(ws + off); off += (size_t)NB * AF * sizeof(unsigned short);
    int* grelC = (int*)(ws + off); off += 1024 * sizeof(int);
    int* grelF = (int*)(ws + off); off += 6400 * sizeof(int);
    int2* binnedC = (int2*)(ws + off); off += (size_t)NCOARSE * CAP_C * sizeof(int2);
    int2* binnedF = (int2*)(ws + off); off += (size_t)NBUCK * CAP_F * sizeof(int2);
    (void)ws_size; (void)n_in;

    hipMemsetAsync(grelC, 0, (1024 + 6400) * sizeof(int), stream);   // grelC + grelF contiguous

    const int ngemm = (NB + 64 * GTILES - 1) / (64 * GTILES);   // 391
    const int npass = (NE + CHUNK1 - 1) / CHUNK1;               // 782
    phase1_kernel<<<ngemm + npass, 256, 0, stream>>>(
        b_input, a_weight, (unsigned int*)Sup, NB,
        edge_rows, edge_cols, edge_vals, grelC, binnedC, NE, NCOARSE, ngemm);
    passA2_kernel<<<NCOARSE * 16, 256, 0, stream>>>(binnedC, grelC, grelF, binnedF, NBUCK);
    spmm_sorted_kernel<<<NBUCK, 256, 0, stream>>>(Sup, binnedF, grelF, a_bias, out, NA);
}